// Round 2
// baseline (35435.150 us; speedup 1.0000x reference)
//
#include <hip/hip_runtime.h>
#include <stdint.h>
#include <stddef.h>

typedef unsigned short u16;
typedef __attribute__((ext_vector_type(8))) short short8;
typedef __attribute__((ext_vector_type(4))) float f32x4;

#define B_    512
#define T_    1024
#define TM1_  1023
#define I_    32
#define E_    32
#define H_    256
#define GSZ   16          // blocks per group
#define NGRP  16          // number of groups
#define NTH   512         // threads per block (8 waves)
#define HBUF  (B_ * H_)   // elems per h state buffer (one parity), bf16 internal
#define OUTY_STRIDE (TM1_ * I_)            // 32736
#define OUTH_BASE ((size_t)B_ * TM1_ * I_) // 16760832

__device__ __forceinline__ u16 f2bf(float f) {
  union { float f; unsigned int i; } c;
  c.f = f;
  unsigned int x = c.i;
  x += 0x7FFFu + ((x >> 16) & 1u);   // round-to-nearest-even
  return (u16)(x >> 16);
}
__device__ __forceinline__ short8 ld8bf(const float* p) {
  short8 rv;
#pragma unroll
  for (int j = 0; j < 8; ++j) rv[j] = (short)f2bf(p[j]);
  return rv;
}
__device__ __forceinline__ float sigm(float x) { return 1.f / (1.f + __expf(-x)); }
__device__ __forceinline__ float tanh_fast(float x) {
  x = fminf(15.f, fmaxf(-15.f, x));
  float e = __expf(2.f * x);
  return (e - 1.f) / (e + 1.f);
}

// Persistent 2-layer GRU. Grid = 256 blocks (1/CU, co-resident), 512 thr.
// 16 groups x 16 blocks. Group g owns batch rows [g*32, g*32+32).
// Block r in group owns h-dims [r*16, r*16+16) (48 gate rows) of both layers.
// Weights live in registers as prebuilt bf16 MFMA B-fragments (converted from
// fp32 once). I/O fp32; internal h ping-pong bf16. 2 group barriers per step.
__global__ __launch_bounds__(NTH, 2)
void arrnn_persistent(
    const float* __restrict__ X, const float* __restrict__ ENC, const int* __restrict__ MASK,
    const float* __restrict__ wih0, const float* __restrict__ whh0,
    const float* __restrict__ bih0, const float* __restrict__ bhh0,
    const float* __restrict__ wih1, const float* __restrict__ whh1,
    const float* __restrict__ bih1, const float* __restrict__ bhh1,
    const float* __restrict__ wout, const float* __restrict__ bout,
    float* __restrict__ out, u16* __restrict__ h0g, u16* __restrict__ h1g,
    int* __restrict__ bars)
{
  // Phase A view: Ainp[32][328] (rows padded +8). Phase B: h0buf[32][264] @0, h1buf @8448
  __shared__ __align__(16) u16 sStage[16896];      // 33,792 B
  __shared__ float sGates[4 * 32 * 16];            //  8,192 B  [gatetile][row][dim]
  __shared__ float sH0loc[32 * 16];                //  2,048 B  fp32 carry, own slice
  __shared__ float sH1loc[32 * 16];                //  2,048 B
  __shared__ float sY[32 * 32];                    //  4,096 B  y(t-1), fp32

  const int tid  = threadIdx.x;
  const int w    = tid >> 6;          // wave 0..7
  const int lane = tid & 63;
  const int quad = lane >> 4;         // 0..3
  const int l15  = lane & 15;
  const int g    = blockIdx.x >> 4;   // group 0..15
  const int r    = blockIdx.x & 15;   // slice 0..15
  const int hs   = r << 4;            // h-dim base of this block's slice
  const int row0 = g << 5;            // batch row base of group
  const int mt   = w & 1;             // M tile (16 rows each)
  const int gt   = w >> 1;            // 0=r, 1=z, 2=i_n, 3=h_n
  const int crow = tid >> 4;          // combine: row 0..31
  const int cdim = tid & 15;          // combine: dim 0..15

  short8 zero8 = {0, 0, 0, 0, 0, 0, 0, 0};

  // ---- preload weight B-fragments into registers (once, fp32 -> bf16) ----
  // B-frag layout (mfma_f32_16x16x32_bf16): lane holds B[k=quad*8+j][n=lane&15];
  // B = W^T, so lane reads 8 contiguous fp32 of W row (gate row = n).
  const int grow = ((gt == 1) ? 256 : (gt >= 2 ? 512 : 0)) + hs + l15;

  short8 wfA[10];   // layer0: r/z K=320 over [wih0|whh0]; i_n K=64; h_n K=256
#pragma unroll
  for (int kk = 0; kk < 10; ++kk) {
    const int k = kk * 32 + quad * 8;
    const float* p;
    bool v;
    if (gt <= 1)      { v = true;     p = (k < 64) ? (wih0 + grow * 64 + k)
                                                   : (whh0 + grow * 256 + (k - 64)); }
    else if (gt == 2) { v = (kk < 2); p = wih0 + grow * 64 + (v ? k : 0); }
    else              { v = (kk < 8); p = whh0 + grow * 256 + (v ? k : 0); }
    wfA[kk] = v ? ld8bf(p) : zero8;
  }

  short8 wfB[16];   // layer1: r/z K=512 over [wih1|whh1]; i_n K=256; h_n K=256
#pragma unroll
  for (int kk = 0; kk < 16; ++kk) {
    const int k = kk * 32 + quad * 8;
    const float* p;
    bool v;
    if (gt <= 1)      { v = true;     p = (k < 256) ? (wih1 + grow * 256 + k)
                                                    : (whh1 + grow * 256 + (k - 256)); }
    else if (gt == 2) { v = (kk < 8); p = wih1 + grow * 256 + (v ? k : 0); }
    else              { v = (kk < 8); p = whh1 + grow * 256 + (v ? k : 0); }
    wfB[kk] = v ? ld8bf(p) : zero8;
  }

  // readout fragments (waves 0..3): y[32 x 32] = h1[32 x 256] @ wout^T
  const int yout = ((w >> 1) & 1) * 16 + l15;   // output dim for this wave
  short8 wfY[8];
  if (w < 4) {
#pragma unroll
    for (int kk = 0; kk < 8; ++kk)
      wfY[kk] = ld8bf(wout + yout * 256 + kk * 32 + quad * 8);
  } else {
#pragma unroll
    for (int kk = 0; kk < 8; ++kk) wfY[kk] = zero8;
  }
  const float boutv = (w < 4) ? bout[yout] : 0.f;

  // per-thread biases for the combine stage (dim = cdim within slice)
  const int bd = hs + cdim;
  const float b0r  = bih0[bd]       + bhh0[bd];
  const float b0z  = bih0[256 + bd] + bhh0[256 + bd];
  const float b0ni = bih0[512 + bd];
  const float b0nh = bhh0[512 + bd];
  const float b1r  = bih1[bd]       + bhh1[bd];
  const float b1z  = bih1[256 + bd] + bhh1[256 + bd];
  const float b1ni = bih1[512 + bd];
  const float b1nh = bhh1[512 + bd];

  sH0loc[tid] = 0.f;
  sH1loc[tid] = 0.f;
  __syncthreads();

  int* cnt = bars + g * 16;   // one monotonic counter per group, 64B apart
  int barTarget = 0;
  int alive = 1;

#define GROUP_BARRIER()                                                          \
  do {                                                                           \
    __syncthreads();                                                             \
    barTarget += GSZ;                                                            \
    if (tid == 0) {                                                              \
      __threadfence();                                                           \
      __hip_atomic_fetch_add(cnt, 1, __ATOMIC_RELAXED, __HIP_MEMORY_SCOPE_AGENT);\
      if (alive) {                                                               \
        int it = 0;                                                              \
        while (__hip_atomic_load(cnt, __ATOMIC_RELAXED,                          \
                                 __HIP_MEMORY_SCOPE_AGENT) < barTarget) {        \
          __builtin_amdgcn_s_sleep(1);                                           \
          if (++it > (1 << 22)) { alive = 0; break; }                            \
        }                                                                        \
      }                                                                          \
      __threadfence();                                                           \
    }                                                                            \
    __syncthreads();                                                             \
  } while (0)

  for (int t = 0; t < 1024; ++t) {
    // ------- readout y(t-1) from h1(t-1), redundant per block (no extra barrier)
    if (t > 0) {
      const u16* h1p = h1g + (t & 1) * HBUF;
      if (w < 4) {
        f32x4 acc = {0.f, 0.f, 0.f, 0.f};
        const u16* ap = h1p + (size_t)(row0 + mt * 16 + l15) * H_ + quad * 8;
#pragma unroll
        for (int kk = 0; kk < 8; ++kk) {
          short8 af = *(const short8*)(ap + kk * 32);
          acc = __builtin_amdgcn_mfma_f32_16x16x32_bf16(af, wfY[kk], acc, 0, 0, 0);
        }
#pragma unroll
        for (int rg = 0; rg < 4; ++rg)
          sY[(mt * 16 + quad * 4 + rg) * 32 + yout] = acc[rg] + boutv;
      }
      __syncthreads();
      if (tid < 64) {   // write this block's 2-row share of the output sequence
        const int lr = r * 2 + (tid >> 5);
        const int lc = tid & 31;
        out[(size_t)(row0 + lr) * OUTY_STRIDE + (size_t)(t - 1) * I_ + lc] =
            sY[lr * 32 + lc];
      }
    }
    if (t == 1023) break;

    // ------- phase A: build Ainp = [x_or_y | e | h0_prev]  (32 x 320, pad 328)
    {
      const int arow = crow;
      const int b    = row0 + arow;
      u16* A = sStage + arow * 328;
      const int c2 = cdim * 2;
      const int keep = (t == 0) ? 1 : (MASK[b * T_ + t] != 0);
      float xv0, xv1;
      if (keep) {
        const float* xp = X + ((size_t)b * T_ + t) * I_ + c2;
        xv0 = xp[0]; xv1 = xp[1];
      } else {
        xv0 = sY[arow * 32 + c2];
        xv1 = sY[arow * 32 + c2 + 1];
      }
      A[c2] = f2bf(xv0); A[c2 + 1] = f2bf(xv1);
      const float* ep = ENC + ((size_t)b * T_ + (t + 1)) * E_ + c2;
      A[32 + c2] = f2bf(ep[0]); A[32 + c2 + 1] = f2bf(ep[1]);
      const int ch = cdim * 16;
      if (t == 0) {
#pragma unroll
        for (int q = 0; q < 16; ++q) A[64 + ch + q] = (u16)0;
      } else {
        const u16* hp = h0g + (t & 1) * HBUF + (size_t)b * H_ + ch;
        *(short8*)(A + 64 + ch)     = *(const short8*)hp;
        *(short8*)(A + 64 + ch + 8) = *(const short8*)(hp + 8);
      }
    }
    __syncthreads();

    // ------- phase A: layer0 GEMM (gates in separate accumulators)
    {
      const int nk   = (gt <= 1) ? 10 : ((gt == 2) ? 2 : 8);
      const int kofs = (gt == 3) ? 64 : 0;
      const u16* ap = sStage + (mt * 16 + l15) * 328 + kofs + quad * 8;
      f32x4 acc = {0.f, 0.f, 0.f, 0.f};
#pragma unroll
      for (int kk = 0; kk < 10; ++kk) {
        if (kk < nk) {
          short8 af = *(const short8*)(ap + kk * 32);
          acc = __builtin_amdgcn_mfma_f32_16x16x32_bf16(af, wfA[kk], acc, 0, 0, 0);
        }
      }
#pragma unroll
      for (int rg = 0; rg < 4; ++rg)
        sGates[(gt * 32 + mt * 16 + quad * 4 + rg) * 16 + l15] = acc[rg];
    }
    __syncthreads();

    // ------- phase A: gate combine -> h0_new (fp32 local carry + bf16 global)
    {
      const float gr = sGates[(0 * 32 + crow) * 16 + cdim] + b0r;
      const float gz = sGates[(1 * 32 + crow) * 16 + cdim] + b0z;
      const float gi = sGates[(2 * 32 + crow) * 16 + cdim] + b0ni;
      const float gh = sGates[(3 * 32 + crow) * 16 + cdim] + b0nh;
      const float rr = sigm(gr);
      const float zz = sigm(gz);
      const float nn = tanh_fast(gi + rr * gh);
      const float hv = (1.f - zz) * nn + zz * sH0loc[tid];
      sH0loc[tid] = hv;
      h0g[((t + 1) & 1) * HBUF + (size_t)(row0 + crow) * H_ + hs + cdim] = f2bf(hv);
    }
    GROUP_BARRIER();   // h0(t) visible group-wide

    // ------- phase B: stage [h0_new | h1_prev] into LDS
    {
      const int arow = crow;
      const int b    = row0 + arow;
      const int ch   = cdim * 16;
      const u16* h0p = h0g + ((t + 1) & 1) * HBUF + (size_t)b * H_ + ch;
      *(short8*)(sStage + arow * 264 + ch)     = *(const short8*)h0p;
      *(short8*)(sStage + arow * 264 + ch + 8) = *(const short8*)(h0p + 8);
      if (t == 0) {
#pragma unroll
        for (int q = 0; q < 16; ++q) sStage[8448 + arow * 264 + ch + q] = (u16)0;
      } else {
        const u16* h1p = h1g + (t & 1) * HBUF + (size_t)b * H_ + ch;
        *(short8*)(sStage + 8448 + arow * 264 + ch)     = *(const short8*)h1p;
        *(short8*)(sStage + 8448 + arow * 264 + ch + 8) = *(const short8*)(h1p + 8);
      }
    }
    __syncthreads();

    // ------- phase B: layer1 GEMM
    {
      const int nk = (gt <= 1) ? 16 : 8;
      f32x4 acc = {0.f, 0.f, 0.f, 0.f};
#pragma unroll
      for (int kk = 0; kk < 16; ++kk) {
        if (kk < nk) {
          int base, k;
          if (gt <= 1)      { base = (kk < 8) ? 0 : 8448; k = (kk & 7) * 32; }
          else if (gt == 2) { base = 0;    k = kk * 32; }
          else              { base = 8448; k = kk * 32; }
          short8 af = *(const short8*)(sStage + base + (mt * 16 + l15) * 264 + k + quad * 8);
          acc = __builtin_amdgcn_mfma_f32_16x16x32_bf16(af, wfB[kk], acc, 0, 0, 0);
        }
      }
#pragma unroll
      for (int rg = 0; rg < 4; ++rg)
        sGates[(gt * 32 + mt * 16 + quad * 4 + rg) * 16 + l15] = acc[rg];
    }
    __syncthreads();

    // ------- phase B: gate combine -> h1_new
    {
      const float gr = sGates[(0 * 32 + crow) * 16 + cdim] + b1r;
      const float gz = sGates[(1 * 32 + crow) * 16 + cdim] + b1z;
      const float gi = sGates[(2 * 32 + crow) * 16 + cdim] + b1ni;
      const float gh = sGates[(3 * 32 + crow) * 16 + cdim] + b1nh;
      const float rr = sigm(gr);
      const float zz = sigm(gz);
      const float nn = tanh_fast(gi + rr * gh);
      const float hv = (1.f - zz) * nn + zz * sH1loc[tid];
      sH1loc[tid] = hv;
      h1g[((t + 1) & 1) * HBUF + (size_t)(row0 + crow) * H_ + hs + cdim] = f2bf(hv);
    }
    GROUP_BARRIER();   // h1(t) visible group-wide
  }

  // final hidden state h1(T-2): each block writes its own fp32 slice
  out[OUTH_BASE + (size_t)(row0 + crow) * H_ + hs + cdim] = sH1loc[tid];
#undef GROUP_BARRIER
}

extern "C" void kernel_launch(void* const* d_in, const int* in_sizes, int n_in,
                              void* d_out, int out_size, void* d_ws, size_t ws_size,
                              hipStream_t stream) {
  (void)in_sizes; (void)n_in; (void)out_size; (void)ws_size;
  const float* X    = (const float*)d_in[0];
  const float* ENC  = (const float*)d_in[1];
  const int*   MASK = (const int*)d_in[2];
  const float* wih0 = (const float*)d_in[3];
  const float* whh0 = (const float*)d_in[4];
  const float* bih0 = (const float*)d_in[5];
  const float* bhh0 = (const float*)d_in[6];
  const float* wih1 = (const float*)d_in[7];
  const float* whh1 = (const float*)d_in[8];
  const float* bih1 = (const float*)d_in[9];
  const float* bhh1 = (const float*)d_in[10];
  const float* wout = (const float*)d_in[11];
  const float* bout = (const float*)d_in[12];
  float* out = (float*)d_out;

  char* ws = (char*)d_ws;
  u16* h0g = (u16*)ws;                                  // 2 x 512x256 bf16
  u16* h1g = (u16*)(ws + 2 * (size_t)HBUF * 2);         // 2 x 512x256 bf16
  int* bars = (int*)(ws + 4 * (size_t)HBUF * 2);        // 16 counters, 64B apart

  hipMemsetAsync(bars, 0, NGRP * 16 * sizeof(int), stream);
  arrnn_persistent<<<dim3(NGRP * GSZ), dim3(NTH), 0, stream>>>(
      X, ENC, MASK, wih0, whh0, bih0, bhh0, wih1, whh1, bih1, bhh1,
      wout, bout, out, h0g, h1g, bars);
}

// Round 4
// 7676.044 us; speedup vs baseline: 4.6163x; 4.6163x over previous
//
#include <hip/hip_runtime.h>
#include <stdint.h>
#include <stddef.h>

typedef unsigned short u16;
typedef unsigned int u32;
typedef unsigned long long u64;
typedef __attribute__((ext_vector_type(8))) short short8;
typedef __attribute__((ext_vector_type(4))) float f32x4;
typedef __attribute__((ext_vector_type(2))) float f32x2;

#define B_    512
#define T_    1024
#define TM1_  1023
#define I_    32
#define E_    32
#define H_    256
#define GSZ   16          // blocks per group
#define NGRP  16          // number of groups
#define NTH   512         // threads per block (8 waves)
#define HBUF  (B_ * H_)   // elems per h state buffer (one parity), bf16 internal
#define OUTY_STRIDE (TM1_ * I_)            // 32736
#define OUTH_BASE ((size_t)B_ * TM1_ * I_) // 16760832

__device__ __forceinline__ u16 f2bf(float f) {
  union { float f; unsigned int i; } c;
  c.f = f;
  unsigned int x = c.i;
  x += 0x7FFFu + ((x >> 16) & 1u);   // round-to-nearest-even
  return (u16)(x >> 16);
}
__device__ __forceinline__ short8 ld8bf(const float* p) {
  short8 rv;
#pragma unroll
  for (int j = 0; j < 8; ++j) rv[j] = (short)f2bf(p[j]);
  return rv;
}
__device__ __forceinline__ float sigm(float x) { return 1.f / (1.f + __expf(-x)); }
__device__ __forceinline__ float tanh_fast(float x) {
  x = fminf(15.f, fmaxf(-15.f, x));
  float e = __expf(2.f * x);
  return (e - 1.f) / (e + 1.f);
}
// volatile => sc0 sc1 on gfx950 (bypass L1 + per-XCD L2, served at the device
// coherence point) AND compiler no-reorder. This is the cross-XCD data path.
__device__ __forceinline__ u64 ldq_cp(const u64* p) { return *(volatile const u64*)p; }
__device__ __forceinline__ void stw_cp(u32* p, u32 v) { *(volatile u32*)p = v; }

// Persistent 2-layer GRU. Grid = 256 blocks (1/CU), 512 thr (8 waves).
// 16 groups x 16 blocks. Group g owns batch rows [g*32,g*32+32); block r owns
// h-dims [r*16,r*16+16) (48 gate rows) of both layers. Weights are
// register-resident bf16 MFMA B-fragments. Cross-block h exchange via
// volatile (sc0 sc1) loads/stores; 2 fence-free group barriers per step.
__global__ __launch_bounds__(NTH, 2)
void arrnn_persistent(
    const float* __restrict__ X, const float* __restrict__ ENC, const int* __restrict__ MASK,
    const float* __restrict__ wih0, const float* __restrict__ whh0,
    const float* __restrict__ bih0, const float* __restrict__ bhh0,
    const float* __restrict__ wih1, const float* __restrict__ whh1,
    const float* __restrict__ bih1, const float* __restrict__ bhh1,
    const float* __restrict__ wout, const float* __restrict__ bout,
    float* __restrict__ out, u16* __restrict__ h0g, u16* __restrict__ h1g,
    int* __restrict__ bars)
{
  __shared__ __align__(16) u16 sH0buf[32 * 264];   // 16896 B  h0 (A-operand k>=64)
  __shared__ __align__(16) u16 sH1buf[32 * 264];   // 16896 B  h1 (readout + phase B)
  __shared__ __align__(16) u16 sXE[32 * 72];       //  4608 B  [x|e] strip (k<64)
  __shared__ float sGates[4 * 32 * 20];            // 10240 B  padded rows (20)
  __shared__ float sH0loc[512];                    //  2048 B  fp32 carry, own slice
  __shared__ float sH1loc[512];
  __shared__ float sY[32 * 36];                    //  4608 B  padded rows (36)

  const int tid  = threadIdx.x;
  const int w    = tid >> 6;          // wave 0..7
  const int lane = tid & 63;
  const int quad = lane >> 4;         // 0..3
  const int l15  = lane & 15;
  const int g    = blockIdx.x >> 4;   // group 0..15
  const int r    = blockIdx.x & 15;   // slice 0..15
  const int hs   = r << 4;            // h-dim base of this block's slice
  const int row0 = g << 5;            // batch row base of group
  const int mt   = w & 1;             // M tile (16 rows each)
  const int gt   = w >> 1;            // 0=r, 1=z, 2=i_n, 3=h_n
  const int crow = tid >> 4;          // staging/combine: row 0..31
  const int cdim = tid & 15;          // staging/combine: dim 0..15

  short8 zero8 = {0, 0, 0, 0, 0, 0, 0, 0};

  // ---- preload weight B-fragments (fp32 -> bf16, once) ----
  // B-frag: lane holds B[k=quad*8+j][n=lane&15]; B=W^T -> 8 contiguous W-row elems.
  const int grow = ((gt == 1) ? 256 : (gt >= 2 ? 512 : 0)) + hs + l15;

  short8 wfA[10];   // layer0: r/z K=320 over [wih0|whh0]; i_n K=64; h_n K=256
#pragma unroll
  for (int kk = 0; kk < 10; ++kk) {
    const int k = kk * 32 + quad * 8;
    const float* p;
    bool v;
    if (gt <= 1)      { v = true;     p = (k < 64) ? (wih0 + grow * 64 + k)
                                                   : (whh0 + grow * 256 + (k - 64)); }
    else if (gt == 2) { v = (kk < 2); p = wih0 + grow * 64 + (v ? k : 0); }
    else              { v = (kk < 8); p = whh0 + grow * 256 + (v ? k : 0); }
    wfA[kk] = v ? ld8bf(p) : zero8;
  }

  short8 wfB[16];   // layer1: r/z K=512 over [wih1|whh1]; i_n K=256; h_n K=256
#pragma unroll
  for (int kk = 0; kk < 16; ++kk) {
    const int k = kk * 32 + quad * 8;
    const float* p;
    bool v;
    if (gt <= 1)      { v = true;     p = (k < 256) ? (wih1 + grow * 256 + k)
                                                    : (whh1 + grow * 256 + (k - 256)); }
    else if (gt == 2) { v = (kk < 8); p = wih1 + grow * 256 + (v ? k : 0); }
    else              { v = (kk < 8); p = whh1 + grow * 256 + (v ? k : 0); }
    wfB[kk] = v ? ld8bf(p) : zero8;
  }

  const int yout = ((w >> 1) & 1) * 16 + l15;
  short8 wfY[8];
  if (w < 4) {
#pragma unroll
    for (int kk = 0; kk < 8; ++kk)
      wfY[kk] = ld8bf(wout + yout * 256 + kk * 32 + quad * 8);
  } else {
#pragma unroll
    for (int kk = 0; kk < 8; ++kk) wfY[kk] = zero8;
  }
  const float boutv = (w < 4) ? bout[yout] : 0.f;

  const int bd = hs + cdim;
  const float b0r  = bih0[bd]       + bhh0[bd];
  const float b0z  = bih0[256 + bd] + bhh0[256 + bd];
  const float b0ni = bih0[512 + bd];
  const float b0nh = bhh0[512 + bd];
  const float b1r  = bih1[bd]       + bhh1[bd];
  const float b1z  = bih1[256 + bd] + bhh1[256 + bd];
  const float b1ni = bih1[512 + bd];
  const float b1nh = bhh1[512 + bd];

  // zero LDS h bufs (t=0 reads them) + fp32 carries
  for (int i = tid; i < 4224; i += NTH) {
    ((u32*)sH0buf)[i] = 0u;
    ((u32*)sH1buf)[i] = 0u;
  }
  sH0loc[tid] = 0.f;
  sH1loc[tid] = 0.f;
  __syncthreads();

  const u64* h0q = (const u64*)h0g;
  const u64* h1q = (const u64*)h1g;
  u32* h0u = (u32*)h0g;
  u32* h1u = (u32*)h1g;

  int* cnt = bars + g * 16;
  int barTarget = 0;
  int alive = 1;

  // Group barrier, no cache-maintenance ops. Producer stores (volatile sc0sc1)
  // are drained by the per-wave s_waitcnt before s_barrier; tid0 additionally
  // waits all counters to 0 before announcing arrival at the coherence point.
#define GROUP_BARRIER()                                                          \
  do {                                                                           \
    asm volatile("" ::: "memory");                                               \
    __syncthreads();                                                             \
    barTarget += GSZ;                                                            \
    if (tid == 0) {                                                              \
      __builtin_amdgcn_s_waitcnt(0);                                             \
      __hip_atomic_fetch_add(cnt, 1, __ATOMIC_RELAXED, __HIP_MEMORY_SCOPE_SYSTEM);\
      int it = 0;                                                                \
      while (alive) {                                                            \
        int v = *(volatile int*)cnt;                                             \
        if (v >= barTarget) break;                                               \
        __builtin_amdgcn_s_sleep(2);                                             \
        if (++it > (1 << 20)) alive = 0;                                         \
      }                                                                          \
    }                                                                            \
    __syncthreads();                                                             \
    asm volatile("" ::: "memory");                                               \
  } while (0)

  const int b = row0 + crow;          // this thread's staging batch row

  for (int t = 0; t < 1024; ++t) {
    const int par = t & 1;

    // ---- loop-top: x/e/mask prefetch + stage h1(t-1) into LDS ----
    int mk = 1;
    f32x2 xld = {0.f, 0.f}, eld = {0.f, 0.f};
    if (t < 1023) {
      xld = *(const f32x2*)(X   + ((size_t)b * T_ + t)     * I_ + 2 * cdim);
      eld = *(const f32x2*)(ENC + ((size_t)b * T_ + t + 1) * E_ + 2 * cdim);
      if (t > 0) mk = (MASK[b * T_ + t] != 0);
    }
    if (t > 0) {
      const u64* hq = h1q + (size_t)par * 32768 + (size_t)b * 64 + cdim * 4;
      u64 q0 = ldq_cp(hq), q1 = ldq_cp(hq + 1), q2 = ldq_cp(hq + 2), q3 = ldq_cp(hq + 3);
      union { u64 q[2]; short8 s; } u0, u1;
      u0.q[0] = q0; u0.q[1] = q1; u1.q[0] = q2; u1.q[1] = q3;
      *(short8*)(sH1buf + crow * 264 + cdim * 16)     = u0.s;
      *(short8*)(sH1buf + crow * 264 + cdim * 16 + 8) = u1.s;
    }
    __syncthreads();

    // ---- readout y(t-1) from sH1buf (redundant per block) ----
    if (t > 0 && w < 4) {
      const u16* ap = sH1buf + (mt * 16 + l15) * 264 + quad * 8;
      f32x4 acc = {0.f, 0.f, 0.f, 0.f};
#pragma unroll
      for (int kk = 0; kk < 8; ++kk) {
        short8 af = *(const short8*)(ap + kk * 32);
        acc = __builtin_amdgcn_mfma_f32_16x16x32_bf16(af, wfY[kk], acc, 0, 0, 0);
      }
#pragma unroll
      for (int rg = 0; rg < 4; ++rg)
        sY[(mt * 16 + quad * 4 + rg) * 36 + yout] = acc[rg] + boutv;
    }
    __syncthreads();

    if (t > 0 && tid < 64) {   // this block's 2-row share of output
      const int lr = r * 2 + (tid >> 5);
      const int lc = tid & 31;
      out[(size_t)(row0 + lr) * OUTY_STRIDE + (size_t)(t - 1) * I_ + lc] =
          sY[lr * 36 + lc];
    }
    if (t == 1023) break;

    // ---- phase A staging: x|e strip (h0_prev already in sH0buf) ----
    {
      u16* A = sXE + crow * 72;
      const int c2 = 2 * cdim;
      float xv0 = mk ? xld.x : sY[crow * 36 + c2];
      float xv1 = mk ? xld.y : sY[crow * 36 + c2 + 1];
      A[c2] = f2bf(xv0);        A[c2 + 1] = f2bf(xv1);
      A[32 + c2] = f2bf(eld.x); A[32 + c2 + 1] = f2bf(eld.y);
    }
    __syncthreads();

    // ---- phase A GEMM: gates from [sXE | sH0buf] ----
    {
      const int arow = mt * 16 + l15;
      f32x4 acc = {0.f, 0.f, 0.f, 0.f};
      if (gt <= 1) {
        const u16* axe = sXE + arow * 72 + quad * 8;
#pragma unroll
        for (int kk = 0; kk < 2; ++kk) {
          short8 af = *(const short8*)(axe + kk * 32);
          acc = __builtin_amdgcn_mfma_f32_16x16x32_bf16(af, wfA[kk], acc, 0, 0, 0);
        }
        const u16* ah = sH0buf + arow * 264 + quad * 8;
#pragma unroll
        for (int kk = 2; kk < 10; ++kk) {
          short8 af = *(const short8*)(ah + (kk - 2) * 32);
          acc = __builtin_amdgcn_mfma_f32_16x16x32_bf16(af, wfA[kk], acc, 0, 0, 0);
        }
      } else if (gt == 2) {
        const u16* axe = sXE + arow * 72 + quad * 8;
#pragma unroll
        for (int kk = 0; kk < 2; ++kk) {
          short8 af = *(const short8*)(axe + kk * 32);
          acc = __builtin_amdgcn_mfma_f32_16x16x32_bf16(af, wfA[kk], acc, 0, 0, 0);
        }
      } else {
        const u16* ah = sH0buf + arow * 264 + quad * 8;
#pragma unroll
        for (int kk = 0; kk < 8; ++kk) {
          short8 af = *(const short8*)(ah + kk * 32);
          acc = __builtin_amdgcn_mfma_f32_16x16x32_bf16(af, wfA[kk], acc, 0, 0, 0);
        }
      }
#pragma unroll
      for (int rg = 0; rg < 4; ++rg)
        sGates[(gt * 32 + mt * 16 + quad * 4 + rg) * 20 + l15] = acc[rg];
    }
    __syncthreads();

    // ---- phase A combine -> h0(t); volatile (sc0sc1) packed store ----
    {
      const float gr = sGates[(0 * 32 + crow) * 20 + cdim] + b0r;
      const float gz = sGates[(1 * 32 + crow) * 20 + cdim] + b0z;
      const float gi = sGates[(2 * 32 + crow) * 20 + cdim] + b0ni;
      const float gh = sGates[(3 * 32 + crow) * 20 + cdim] + b0nh;
      const float rr = sigm(gr);
      const float zz = sigm(gz);
      const float nn = tanh_fast(gi + rr * gh);
      const float hv = (1.f - zz) * nn + zz * sH0loc[tid];
      sH0loc[tid] = hv;
      const float hp = __shfl_xor(hv, 1, 64);
      if (!(tid & 1)) {
        u32 pk = (u32)f2bf(hv) | ((u32)f2bf(hp) << 16);
        stw_cp(h0u + (size_t)(par ^ 1) * 65536 + (size_t)b * 128 + ((hs + cdim) >> 1), pk);
      }
    }
    GROUP_BARRIER();   // h0(t) at coherence point, group-wide

    // ---- phase B staging: h0(t) -> sH0buf (also next step's A-operand) ----
    {
      const u64* hq = h0q + (size_t)(par ^ 1) * 32768 + (size_t)b * 64 + cdim * 4;
      u64 q0 = ldq_cp(hq), q1 = ldq_cp(hq + 1), q2 = ldq_cp(hq + 2), q3 = ldq_cp(hq + 3);
      union { u64 q[2]; short8 s; } u0, u1;
      u0.q[0] = q0; u0.q[1] = q1; u1.q[0] = q2; u1.q[1] = q3;
      *(short8*)(sH0buf + crow * 264 + cdim * 16)     = u0.s;
      *(short8*)(sH0buf + crow * 264 + cdim * 16 + 8) = u1.s;
    }
    __syncthreads();

    // ---- phase B GEMM: gates from [sH0buf | sH1buf] ----
    {
      const int arow = mt * 16 + l15;
      f32x4 acc = {0.f, 0.f, 0.f, 0.f};
      if (gt <= 1) {
        const u16* a0 = sH0buf + arow * 264 + quad * 8;
#pragma unroll
        for (int kk = 0; kk < 8; ++kk) {
          short8 af = *(const short8*)(a0 + kk * 32);
          acc = __builtin_amdgcn_mfma_f32_16x16x32_bf16(af, wfB[kk], acc, 0, 0, 0);
        }
        const u16* a1 = sH1buf + arow * 264 + quad * 8;
#pragma unroll
        for (int kk = 0; kk < 8; ++kk) {
          short8 af = *(const short8*)(a1 + kk * 32);
          acc = __builtin_amdgcn_mfma_f32_16x16x32_bf16(af, wfB[kk + 8], acc, 0, 0, 0);
        }
      } else if (gt == 2) {
        const u16* a0 = sH0buf + arow * 264 + quad * 8;
#pragma unroll
        for (int kk = 0; kk < 8; ++kk) {
          short8 af = *(const short8*)(a0 + kk * 32);
          acc = __builtin_amdgcn_mfma_f32_16x16x32_bf16(af, wfB[kk], acc, 0, 0, 0);
        }
      } else {
        const u16* a1 = sH1buf + arow * 264 + quad * 8;
#pragma unroll
        for (int kk = 0; kk < 8; ++kk) {
          short8 af = *(const short8*)(a1 + kk * 32);
          acc = __builtin_amdgcn_mfma_f32_16x16x32_bf16(af, wfB[kk], acc, 0, 0, 0);
        }
      }
#pragma unroll
      for (int rg = 0; rg < 4; ++rg)
        sGates[(gt * 32 + mt * 16 + quad * 4 + rg) * 20 + l15] = acc[rg];
    }
    __syncthreads();

    // ---- phase B combine -> h1(t); volatile (sc0sc1) packed store ----
    {
      const float gr = sGates[(0 * 32 + crow) * 20 + cdim] + b1r;
      const float gz = sGates[(1 * 32 + crow) * 20 + cdim] + b1z;
      const float gi = sGates[(2 * 32 + crow) * 20 + cdim] + b1ni;
      const float gh = sGates[(3 * 32 + crow) * 20 + cdim] + b1nh;
      const float rr = sigm(gr);
      const float zz = sigm(gz);
      const float nn = tanh_fast(gi + rr * gh);
      const float hv = (1.f - zz) * nn + zz * sH1loc[tid];
      sH1loc[tid] = hv;
      const float hp = __shfl_xor(hv, 1, 64);
      if (!(tid & 1)) {
        u32 pk = (u32)f2bf(hv) | ((u32)f2bf(hp) << 16);
        stw_cp(h1u + (size_t)(par ^ 1) * 65536 + (size_t)b * 128 + ((hs + cdim) >> 1), pk);
      }
    }
    GROUP_BARRIER();   // h1(t) at coherence point, group-wide
  }

  // final hidden state h1(T-2): own fp32 slice
  out[OUTH_BASE + (size_t)b * H_ + hs + cdim] = sH1loc[tid];
#undef GROUP_BARRIER
}

extern "C" void kernel_launch(void* const* d_in, const int* in_sizes, int n_in,
                              void* d_out, int out_size, void* d_ws, size_t ws_size,
                              hipStream_t stream) {
  (void)in_sizes; (void)n_in; (void)out_size; (void)ws_size;
  const float* X    = (const float*)d_in[0];
  const float* ENC  = (const float*)d_in[1];
  const int*   MASK = (const int*)d_in[2];
  const float* wih0 = (const float*)d_in[3];
  const float* whh0 = (const float*)d_in[4];
  const float* bih0 = (const float*)d_in[5];
  const float* bhh0 = (const float*)d_in[6];
  const float* wih1 = (const float*)d_in[7];
  const float* whh1 = (const float*)d_in[8];
  const float* bih1 = (const float*)d_in[9];
  const float* bhh1 = (const float*)d_in[10];
  const float* wout = (const float*)d_in[11];
  const float* bout = (const float*)d_in[12];
  float* out = (float*)d_out;

  char* ws = (char*)d_ws;
  u16* h0g = (u16*)ws;                                  // 2 x 512x256 bf16
  u16* h1g = (u16*)(ws + 2 * (size_t)HBUF * 2);         // 2 x 512x256 bf16
  int* bars = (int*)(ws + 4 * (size_t)HBUF * 2);        // 16 counters, 64B apart

  hipMemsetAsync(bars, 0, NGRP * 16 * sizeof(int), stream);
  arrnn_persistent<<<dim3(NGRP * GSZ), dim3(NTH), 0, stream>>>(
      X, ENC, MASK, wih0, whh0, bih0, bhh0, wih1, whh1, bih1, bhh1,
      wout, bout, out, h0g, h1g, bars);
}